// Round 1
// baseline (3042.877 us; speedup 1.0000x reference)
//
#include <hip/hip_runtime.h>

#define N_EDGES  800000
#define N_NODES  50000
#define IN_DIM   64
#define EDGE_DIM 32
#define HID      96
#define OUT_DIM  64

// ---------------------------------------------------------------------------
// Kernel 1: zero the output accumulator and the per-node counts.
// ---------------------------------------------------------------------------
__global__ __launch_bounds__(256) void zero_kernel(float* __restrict__ out,
                                                   float* __restrict__ cnt) {
    int i = blockIdx.x * 256 + threadIdx.x;
    int total = N_NODES * OUT_DIM;
    if (i < total) out[i] = 0.0f;
    if (i < N_NODES) cnt[i] = 0.0f;
}

// ---------------------------------------------------------------------------
// Kernel 2: per-edge MLP + atomic scatter-add.
// One thread per edge. Weights staged in LDS (all lanes read the same
// address per step -> LDS broadcast, conflict-free).
// ---------------------------------------------------------------------------
__global__ __launch_bounds__(256, 2) void edge_mlp_kernel(
    const float* __restrict__ x,
    const int*   __restrict__ ei,     // [2, E] int32
    const float* __restrict__ ea,
    const float* __restrict__ W1,     // [HID, HID] row-major
    const float* __restrict__ b1,     // [HID]
    const float* __restrict__ W2,     // [HID, OUT] row-major
    const float* __restrict__ b2,     // [OUT]
    float*       __restrict__ out,    // [N, OUT] accumulator
    float*       __restrict__ cnt)    // [N]
{
    __shared__ float sW1[HID * HID];
    __shared__ float sW2[HID * OUT_DIM];
    __shared__ float sb1[HID];
    __shared__ float sb2[OUT_DIM];

    for (int i = threadIdx.x; i < HID * HID; i += 256) sW1[i] = W1[i];
    for (int i = threadIdx.x; i < HID * OUT_DIM; i += 256) sW2[i] = W2[i];
    if (threadIdx.x < HID) sb1[threadIdx.x] = b1[threadIdx.x];
    if (threadIdx.x < OUT_DIM) sb2[threadIdx.x] = b2[threadIdx.x];
    __syncthreads();

    int e = blockIdx.x * 256 + threadIdx.x;
    if (e >= N_EDGES) return;

    int r = ei[e];            // source node
    int c = ei[N_EDGES + e];  // destination node

    // Load input vector h = [x[r], edge_attr[e]]  (96 floats, vectorized)
    float h[HID];
    {
        const float4* xr = reinterpret_cast<const float4*>(x + (size_t)r * IN_DIM);
        #pragma unroll
        for (int k = 0; k < IN_DIM / 4; ++k) {
            float4 v = xr[k];
            h[4 * k + 0] = v.x; h[4 * k + 1] = v.y;
            h[4 * k + 2] = v.z; h[4 * k + 3] = v.w;
        }
        const float4* ep = reinterpret_cast<const float4*>(ea + (size_t)e * EDGE_DIM);
        #pragma unroll
        for (int k = 0; k < EDGE_DIM / 4; ++k) {
            float4 v = ep[k];
            h[IN_DIM + 4 * k + 0] = v.x; h[IN_DIM + 4 * k + 1] = v.y;
            h[IN_DIM + 4 * k + 2] = v.z; h[IN_DIM + 4 * k + 3] = v.w;
        }
    }

    // Output accumulators, init with b2.
    float acc[OUT_DIM];
    #pragma unroll
    for (int o = 0; o < OUT_DIM; ++o) acc[o] = sb2[o];

    // Stream over hidden units: hj = relu(b1[j] + h . W1[:,j]);
    // acc[o] += hj * W2[j,o]
    for (int j = 0; j < HID; ++j) {
        float hj = sb1[j];
        #pragma unroll
        for (int k = 0; k < HID; ++k) hj = fmaf(h[k], sW1[k * HID + j], hj);
        hj = fmaxf(hj, 0.0f);
        #pragma unroll
        for (int o = 0; o < OUT_DIM; ++o) acc[o] = fmaf(hj, sW2[j * OUT_DIM + o], acc[o]);
    }

    // Scatter.
    float* op = out + (size_t)c * OUT_DIM;
    #pragma unroll
    for (int o = 0; o < OUT_DIM; ++o) atomicAdd(op + o, acc[o]);
    atomicAdd(cnt + c, 1.0f);
}

// ---------------------------------------------------------------------------
// Kernel 3: divide by max(count, 1).
// ---------------------------------------------------------------------------
__global__ __launch_bounds__(256) void div_kernel(float* __restrict__ out,
                                                  const float* __restrict__ cnt) {
    int i = blockIdx.x * 256 + threadIdx.x;
    if (i < N_NODES * OUT_DIM) {
        float c = cnt[i / OUT_DIM];
        out[i] = out[i] / fmaxf(c, 1.0f);
    }
}

extern "C" void kernel_launch(void* const* d_in, const int* in_sizes, int n_in,
                              void* d_out, int out_size, void* d_ws, size_t ws_size,
                              hipStream_t stream) {
    const float* x  = (const float*)d_in[0];
    const int*   ei = (const int*)d_in[1];
    const float* ea = (const float*)d_in[2];
    const float* W1 = (const float*)d_in[3];
    const float* b1 = (const float*)d_in[4];
    const float* W2 = (const float*)d_in[5];
    const float* b2 = (const float*)d_in[6];
    float* out = (float*)d_out;
    float* cnt = (float*)d_ws;  // N_NODES floats

    {
        int total = N_NODES * OUT_DIM;
        int blocks = (total + 255) / 256;
        zero_kernel<<<blocks, 256, 0, stream>>>(out, cnt);
    }
    {
        int blocks = (N_EDGES + 255) / 256;
        edge_mlp_kernel<<<blocks, 256, 0, stream>>>(x, ei, ea, W1, b1, W2, b2, out, cnt);
    }
    {
        int total = N_NODES * OUT_DIM;
        int blocks = (total + 255) / 256;
        div_kernel<<<blocks, 256, 0, stream>>>(out, cnt);
    }
}

// Round 2
// 232.113 us; speedup vs baseline: 13.1095x; 13.1095x over previous
//
#include <hip/hip_runtime.h>

#define N_EDGES  800000
#define N_NODES  50000
#define IN_DIM   64
#define EDGE_DIM 32
#define HID      96
#define OUT_DIM  64
#define BE       128              // edges per tile
#define PAD      104              // padded LDS row length (bf16) -> 208 B, 16B-aligned, ~2-way banks
#define NTILES   (N_EDGES / BE)   // 6250 exactly

typedef __attribute__((ext_vector_type(8))) short  short8;
typedef __attribute__((ext_vector_type(8))) ushort ushort8;
typedef __attribute__((ext_vector_type(4))) float  f32x4;

__device__ inline ushort f2bf(float f) {
    union { float f; unsigned u; } v; v.f = f;
    unsigned r = v.u + 0x7FFFu + ((v.u >> 16) & 1u);   // round-to-nearest-even
    return (ushort)(r >> 16);
}

// ---------------------------------------------------------------------------
// Kernel 1: zero output accumulator + counts.
// ---------------------------------------------------------------------------
__global__ __launch_bounds__(256) void zero_kernel(float* __restrict__ out,
                                                   float* __restrict__ cnt) {
    int i = blockIdx.x * 256 + threadIdx.x;
    if (i < N_NODES * OUT_DIM) out[i] = 0.0f;
    if (i < N_NODES) cnt[i] = 0.0f;
}

// ---------------------------------------------------------------------------
// Kernel 2: fused gather -> bf16 MFMA MLP -> atomic scatter.
// 256 threads = 4 waves; each wave owns 32 edge-rows of the tile end-to-end,
// so the tile loop needs no __syncthreads (same-wave DS ops are in-order;
// lgkmcnt(0) fences the cross-lane LDS handoffs).
// ---------------------------------------------------------------------------
__global__ __launch_bounds__(256, 2) void edge_mlp_mfma_kernel(
    const float* __restrict__ x,
    const int*   __restrict__ ei,     // [2, E] int32
    const float* __restrict__ ea,
    const float* __restrict__ W1,     // [HID, HID] row-major (k, n)
    const float* __restrict__ b1,
    const float* __restrict__ W2,     // [HID, OUT] row-major (k, n)
    const float* __restrict__ b2,
    float*       __restrict__ out,    // [N, OUT] accumulator
    float*       __restrict__ cnt)    // [N]
{
    __shared__ ushort sA[BE][PAD];        // input tile, then H (reused)
    __shared__ ushort sW1T[HID][PAD];     // W1 transposed: [n][k]
    __shared__ ushort sW2T[OUT_DIM][PAD]; // W2 transposed: [n][k]
    __shared__ float  sb1[HID];
    __shared__ float  sb2[OUT_DIM];

    const int tid  = threadIdx.x;
    const int wave = tid >> 6;
    const int lane = tid & 63;
    const int lr   = lane & 15;   // frag row/col index
    const int lg   = lane >> 4;   // k-group / row-group
    const int el_base = wave * 32;

    // ---- stage weights (bf16, transposed) once per block ----
    for (int i = tid; i < HID * HID; i += 256) {
        int k = i / HID, n = i % HID;
        sW1T[n][k] = f2bf(W1[i]);
    }
    for (int i = tid; i < HID * OUT_DIM; i += 256) {
        int k = i / OUT_DIM, n = i % OUT_DIM;
        sW2T[n][k] = f2bf(W2[i]);
    }
    if (tid < HID) sb1[tid] = b1[tid];
    if (tid < OUT_DIM) sb2[tid] = b2[tid];
    __syncthreads();

    for (int tl = blockIdx.x; tl < NTILES; tl += gridDim.x) {
        const int e0 = tl * BE;

        // ---- gather: 2 threads per edge; wave gathers exactly its own rows ----
        {
            const int el   = el_base + (lane >> 1);
            const int part = lane & 1;
            const int e    = e0 + el;
            const int row  = ei[e];
            const float4* xp = reinterpret_cast<const float4*>(x) + (size_t)row * 16 + part * 8;
            #pragma unroll
            for (int i = 0; i < 4; ++i) {
                float4 a = xp[2 * i], b = xp[2 * i + 1];
                ushort8 v = { f2bf(a.x), f2bf(a.y), f2bf(a.z), f2bf(a.w),
                              f2bf(b.x), f2bf(b.y), f2bf(b.z), f2bf(b.w) };
                *(ushort8*)&sA[el][part * 32 + i * 8] = v;
            }
            const float4* ep = reinterpret_cast<const float4*>(ea) + (size_t)e * 8 + part * 4;
            #pragma unroll
            for (int i = 0; i < 2; ++i) {
                float4 a = ep[2 * i], b = ep[2 * i + 1];
                ushort8 v = { f2bf(a.x), f2bf(a.y), f2bf(a.z), f2bf(a.w),
                              f2bf(b.x), f2bf(b.y), f2bf(b.z), f2bf(b.w) };
                *(ushort8*)&sA[el][64 + part * 16 + i * 8] = v;
            }
            if (part == 0) atomicAdd(cnt + ei[N_EDGES + e], 1.0f);
        }
        asm volatile("s_waitcnt lgkmcnt(0)" ::: "memory");

        // ---- GEMM1: H = relu(A @ W1 + b1), A = sA[32 rows x 96] ----
        short8 af[2][3];
        #pragma unroll
        for (int mt = 0; mt < 2; ++mt)
            #pragma unroll
            for (int ks = 0; ks < 3; ++ks)
                af[mt][ks] = *(const short8*)&sA[el_base + mt * 16 + lr][ks * 32 + lg * 8];

        f32x4 acc1[2][6];
        #pragma unroll
        for (int nt = 0; nt < 6; ++nt) {
            float bv = sb1[nt * 16 + lr];
            acc1[0][nt] = f32x4{ bv, bv, bv, bv };
            acc1[1][nt] = f32x4{ bv, bv, bv, bv };
        }
        #pragma unroll
        for (int nt = 0; nt < 6; ++nt) {
            short8 bf[3];
            #pragma unroll
            for (int ks = 0; ks < 3; ++ks)
                bf[ks] = *(const short8*)&sW1T[nt * 16 + lr][ks * 32 + lg * 8];
            #pragma unroll
            for (int mt = 0; mt < 2; ++mt)
                #pragma unroll
                for (int ks = 0; ks < 3; ++ks)
                    acc1[mt][nt] = __builtin_amdgcn_mfma_f32_16x16x32_bf16(
                        af[mt][ks], bf[ks], acc1[mt][nt], 0, 0, 0);
        }

        // ---- ReLU + write H back over sA (bf16). D layout: col=lr, row=lg*4+j ----
        #pragma unroll
        for (int mt = 0; mt < 2; ++mt)
            #pragma unroll
            for (int nt = 0; nt < 6; ++nt)
                #pragma unroll
                for (int j = 0; j < 4; ++j)
                    sA[el_base + mt * 16 + lg * 4 + j][nt * 16 + lr] =
                        f2bf(fmaxf(acc1[mt][nt][j], 0.0f));
        asm volatile("s_waitcnt lgkmcnt(0)" ::: "memory");

        // ---- GEMM2: O = H @ W2 + b2 ----
        short8 a2[2][3];
        #pragma unroll
        for (int mt = 0; mt < 2; ++mt)
            #pragma unroll
            for (int ks = 0; ks < 3; ++ks)
                a2[mt][ks] = *(const short8*)&sA[el_base + mt * 16 + lr][ks * 32 + lg * 8];

        f32x4 acc2[2][4];
        #pragma unroll
        for (int nt = 0; nt < 4; ++nt) {
            float bv = sb2[nt * 16 + lr];
            acc2[0][nt] = f32x4{ bv, bv, bv, bv };
            acc2[1][nt] = f32x4{ bv, bv, bv, bv };
        }
        #pragma unroll
        for (int nt = 0; nt < 4; ++nt) {
            short8 bf[3];
            #pragma unroll
            for (int ks = 0; ks < 3; ++ks)
                bf[ks] = *(const short8*)&sW2T[nt * 16 + lr][ks * 32 + lg * 8];
            #pragma unroll
            for (int mt = 0; mt < 2; ++mt)
                #pragma unroll
                for (int ks = 0; ks < 3; ++ks)
                    acc2[mt][nt] = __builtin_amdgcn_mfma_f32_16x16x32_bf16(
                        a2[mt][ks], bf[ks], acc2[mt][nt], 0, 0, 0);
        }

        // ---- scatter: out[col[e]][o] += acc2 ----
        #pragma unroll
        for (int mt = 0; mt < 2; ++mt) {
            int nd[4];
            #pragma unroll
            for (int j = 0; j < 4; ++j)
                nd[j] = ei[N_EDGES + e0 + el_base + mt * 16 + lg * 4 + j];
            #pragma unroll
            for (int nt = 0; nt < 4; ++nt)
                #pragma unroll
                for (int j = 0; j < 4; ++j)
                    atomicAdd(out + (size_t)nd[j] * OUT_DIM + nt * 16 + lr,
                              acc2[mt][nt][j]);
        }
    }
}

// ---------------------------------------------------------------------------
// Kernel 3: divide by max(count, 1).
// ---------------------------------------------------------------------------
__global__ __launch_bounds__(256) void div_kernel(float* __restrict__ out,
                                                  const float* __restrict__ cnt) {
    int i = blockIdx.x * 256 + threadIdx.x;
    if (i < N_NODES * OUT_DIM) {
        float c = cnt[i / OUT_DIM];
        out[i] = out[i] / fmaxf(c, 1.0f);
    }
}

extern "C" void kernel_launch(void* const* d_in, const int* in_sizes, int n_in,
                              void* d_out, int out_size, void* d_ws, size_t ws_size,
                              hipStream_t stream) {
    const float* x  = (const float*)d_in[0];
    const int*   ei = (const int*)d_in[1];
    const float* ea = (const float*)d_in[2];
    const float* W1 = (const float*)d_in[3];
    const float* b1 = (const float*)d_in[4];
    const float* W2 = (const float*)d_in[5];
    const float* b2 = (const float*)d_in[6];
    float* out = (float*)d_out;
    float* cnt = (float*)d_ws;  // N_NODES floats

    {
        int blocks = (N_NODES * OUT_DIM + 255) / 256;
        zero_kernel<<<blocks, 256, 0, stream>>>(out, cnt);
    }
    edge_mlp_mfma_kernel<<<2048, 256, 0, stream>>>(x, ei, ea, W1, b1, W2, b2, out, cnt);
    {
        int blocks = (N_NODES * OUT_DIM + 255) / 256;
        div_kernel<<<blocks, 256, 0, stream>>>(out, cnt);
    }
}